// Round 3
// baseline (234819.653 us; speedup 1.0000x reference)
//
#include <hip/hip_runtime.h>
#include <math.h>

// Problem constants
#define TT 2048
#define HZ 16
#define NBLK 16

// d_out layout (floats): pred | attw | q_gru_n | dec_gru_n | query_n
#define OUT_ATTW   (2048*64*64)            // 8388608
#define OUT_QGRU   (OUT_ATTW + 2048*8*64)  // 9437184
#define OUT_DECGRU (OUT_QGRU + 256)        // 9437440
#define OUT_QN     (OUT_DECGRU + 256)      // 9437696

// d_ws layout (bytes)
#define WSO_MB     0                        // ulong mailbox[2][16][32] = 8192 B
#define WSO_GIFIX  8192                     // float[2048][768]
#define WSO_HIDFIX (WSO_GIFIX + 2048*768*4)         // float[2048][256]
#define WSO_QHWTH  (WSO_HIDFIX + 2048*256*4)        // float[256][256]
#define WSO_QHWTA  (WSO_QHWTH + 256*256*4)          // float[512][256]
#define WSO_W2T    (WSO_QHWTA + 512*256*4)          // float[256][64]
#define WSO_DAVA   (WSO_W2T + 256*64*4)             // float[2048][512]
#define WSO_DECH   (WSO_DAVA + 2048*512*4)          // float[2048][256]
#define WSO_FEAT   (WSO_DECH + 2048*256*4)          // float[2048][832]
#define WSO_SBUF   (WSO_FEAT + 2048*832*4)          // float[2048][256]

__device__ __forceinline__ float warp_sum(float v) {
#pragma unroll
  for (int o = 32; o > 0; o >>= 1) v += __shfl_down(v, o, 64);
  return v;
}
__device__ __forceinline__ float warp_max(float v) {
#pragma unroll
  for (int o = 32; o > 0; o >>= 1) v = fmaxf(v, __shfl_down(v, o, 64));
  return v;
}
__device__ __forceinline__ float sigf(float x) { return 1.f / (1.f + __expf(-x)); }
__device__ __forceinline__ float dot4(float4 a, float4 b) {
  return a.x*b.x + a.y*b.y + a.z*b.z + a.w*b.w;
}
__device__ __forceinline__ unsigned long long aload64(const unsigned long long* p) {
  return __hip_atomic_load(p, __ATOMIC_RELAXED, __HIP_MEMORY_SCOPE_AGENT);
}
__device__ __forceinline__ void astore64(unsigned long long* p, unsigned long long v) {
  __hip_atomic_store(p, v, __ATOMIC_RELAXED, __HIP_MEMORY_SCOPE_AGENT);
}
__device__ __forceinline__ unsigned long long mbpack(float f, unsigned tag) {
  return ((unsigned long long)tag << 32) | (unsigned long long)__float_as_uint(f);
}

// ---------------- transposes: q_hid_w cols, dec_out_w ----------------
__global__ void transpose_k(const float* __restrict__ qhw,  // [256,832]
                            const float* __restrict__ w2,   // [64,256]
                            float* __restrict__ qhwT_h,     // [256][256] (cols 0:256)
                            float* __restrict__ qhwT_a,     // [512][256] (cols 320:832)
                            float* __restrict__ w2T) {      // [256,64]
  int g = blockIdx.x * 256 + threadIdx.x;
  if (g < 65536) {
    int k = g >> 8, r = g & 255;
    qhwT_h[g] = qhw[r * 832 + k];
  } else if (g < 196608) {
    int e = g - 65536;
    int k = e >> 8, r = e & 255;
    qhwT_a[e] = qhw[r * 832 + 320 + k];
  } else {
    int e = g - 196608;
    int r = e >> 6, a = e & 63;
    w2T[e] = w2[a * 256 + r];
  }
}

// ---------------- generic tiled GEMM: C[t][r] = bias[r] + sum_k X[t][k]*W[r][woff+k]
__global__ void __launch_bounds__(256) gemm64(
    const float* __restrict__ X, int ldx,
    const float* __restrict__ W, int ldw, int woff,
    const float* __restrict__ bias,
    float* __restrict__ C, int crows, int K) {
  __shared__ float Xs[64 * 65];
  __shared__ float Ws[64 * 65];
  int t0 = blockIdx.x * 64, r0 = blockIdx.y * 64;
  int tid = threadIdx.x;
  int u = tid & 15, v = tid >> 4;
  float acc[4][4];
#pragma unroll
  for (int i = 0; i < 4; i++)
#pragma unroll
    for (int j = 0; j < 4; j++) acc[i][j] = 0.f;

  for (int kc = 0; kc < K; kc += 64) {
    for (int idx = tid; idx < 4096; idx += 256) {
      int row = idx >> 6, col = idx & 63;
      Xs[row * 65 + col] = X[(size_t)(t0 + row) * ldx + kc + col];
      Ws[row * 65 + col] = W[(size_t)(r0 + row) * ldw + woff + kc + col];
    }
    __syncthreads();
#pragma unroll 8
    for (int k = 0; k < 64; k++) {
      float xs[4], ws[4];
#pragma unroll
      for (int i = 0; i < 4; i++) xs[i] = Xs[(v + 16 * i) * 65 + k];
#pragma unroll
      for (int j = 0; j < 4; j++) ws[j] = Ws[(u + 16 * j) * 65 + k];
#pragma unroll
      for (int i = 0; i < 4; i++)
#pragma unroll
        for (int j = 0; j < 4; j++) acc[i][j] += xs[i] * ws[j];
    }
    __syncthreads();
  }
#pragma unroll
  for (int i = 0; i < 4; i++)
#pragma unroll
    for (int j = 0; j < 4; j++) {
      int t = t0 + v + 16 * i, r = r0 + u + 16 * j;
      C[(size_t)t * crows + r] = acc[i][j] + bias[r];
    }
}

// ---------------- fused sequential kernel: 1 data-carrying barrier/step -------
__global__ void __launch_bounds__(256) seq_kernel(
    const float* __restrict__ x_fix,    // [2048,64]
    const float* __restrict__ x_att,    // [2048,64,64]
    const float* __restrict__ w_ih,     // [768,1088]
    const float* __restrict__ w_hh,     // [768,256]
    const float* __restrict__ b_hh,     // [768]
    const float* __restrict__ qhwT_h,   // [256][256]
    const float* __restrict__ qhwT_a,   // [512][256]
    const float* __restrict__ wq,       // [256,512]
    const float* __restrict__ dwih,     // [768,576]
    const float* __restrict__ dwhh,     // [768,256]
    const float* __restrict__ dbih,     // [768]
    const float* __restrict__ dbhh,     // [768]
    const float* __restrict__ gi_fix,   // [2048,768]
    const float* __restrict__ hid_fix,  // [2048,256]
    unsigned long long* __restrict__ mb,  // [2][512] (tag<<32|payload)
    float* __restrict__ dava,           // [2048,512]
    float* __restrict__ dec_hist,       // [2048,256]
    float* __restrict__ out) {
  __shared__ float att_s[64 * 65];             // x_att tile (t)
  __shared__ float ring_s[16][512];            // attw ring
  __shared__ __align__(16) float avq_s[1024];  // [attv(512) | query(512)]
  __shared__ float qk_s[512];                  // attw(t)
  __shared__ __align__(16) float xcat_s[576];  // [fix(64) | dec_att_a(512)]
  __shared__ float hid_s[256];
  __shared__ __align__(16) float h_s[256];
  __shared__ __align__(16) float dech_s[256];
  __shared__ float g_s[4][16];
  __shared__ float dg_s[4][16];

  const int tid = threadIdx.x;
  const int bid = blockIdx.x;
  const int lane = tid & 63, wv = tid >> 6;
  const int h0 = wv * 2;

  // init
  for (int i = tid; i < 512; i += 256) avq_s[512 + i] = 1.f;  // q(0) = ones
  h_s[tid] = 0.f;
  dech_s[tid] = 0.f;
  for (int idx = tid; idx < 4096; idx += 256)
    att_s[(idx >> 6) * 65 + (idx & 63)] = x_att[idx];
  __syncthreads();

  for (int t = 0; t <= TT; ++t) {
    if (t > 0) {
      // ---- poll mailbox (parity of t-1), tags == t; payload IS the data ----
      unsigned long long* base = mb + (size_t)((t - 1) & 1) * 512;
      const unsigned tg = (unsigned)t;
      unsigned long long v0 = aload64(base + tid);
      unsigned long long v1 = aload64(base + tid + 256);
      while ((unsigned)(v0 >> 32) != tg) {
        __builtin_amdgcn_s_sleep(2);
        v0 = aload64(base + tid);
      }
      while ((unsigned)(v1 >> 32) != tg) {
        __builtin_amdgcn_s_sleep(2);
        v1 = aload64(base + tid + 256);
      }
      {
        int b0 = tid >> 5, j0 = tid & 31;
        float f0 = __uint_as_float((unsigned)v0);
        if (j0 < 16) h_s[b0 * 16 + j0] = f0; else dech_s[b0 * 16 + j0 - 16] = f0;
        int c1 = tid + 256, b1 = c1 >> 5, j1 = c1 & 31;
        float f1 = __uint_as_float((unsigned)v1);
        if (j1 < 16) h_s[b1 * 16 + j1] = f1; else dech_s[b1 * 16 + j1 - 16] = f1;
      }
      __syncthreads();
      // ---- replicated hid(t-1) = relu(qhw@[h2,fix,attv]+b): row = tid ----
      {
        float acc = hid_fix[(size_t)(t - 1) * 256 + tid];
        const float* Wh = qhwT_h + tid;
        const float* Wa = qhwT_a + tid;
#pragma unroll 4
        for (int k = 0; k < 256; k++) acc += Wh[(size_t)k * 256] * h_s[k];
#pragma unroll 4
        for (int k = 0; k < 512; k++) acc += Wa[(size_t)k * 256] * avq_s[k];
        hid_s[tid] = fmaxf(acc, 0.f);
      }
      __syncthreads();
      // ---- replicated q(t) = hid @ wq: each thread 2 adjacent cols ----
      {
        float a0 = 0.f, a1 = 0.f;
#pragma unroll 4
        for (int r = 0; r < 256; r++) {
          float hv = hid_s[r];
          float2 w = ((const float2*)(wq + (size_t)r * 512))[tid];
          a0 += hv * w.x;
          a1 += hv * w.y;
        }
        avq_s[512 + 2 * tid] = a0;
        avq_s[512 + 2 * tid + 1] = a1;
        if (t == TT) {
          if (bid == 0) {
            out[OUT_QGRU + tid] = h_s[tid];
            out[OUT_DECGRU + tid] = dech_s[tid];
            out[OUT_QN + 2 * tid] = a0;
            out[OUT_QN + 2 * tid + 1] = a1;
          }
          break;
        }
      }
      __syncthreads();
    }

    // ---- attention(t): attw, attv, dec_att_a (replicated) ----
    if (tid < 64) xcat_s[tid] = x_fix[t * 64 + tid];
    {
      float acc0 = 0.f, acc1 = 0.f;
#pragma unroll 16
      for (int a2 = 0; a2 < 64; a2++) {
        float xv = att_s[lane * 65 + a2];
        acc0 += avq_s[512 + h0 * 64 + a2] * xv;
        acc1 += avq_s[512 + h0 * 64 + 64 + a2] * xv;
      }
      acc0 *= 0.125f;
      acc1 *= 0.125f;
      float m0 = __shfl(warp_max(acc0), 0, 64);
      float e0 = __expf(acc0 - m0);
      float s0 = __shfl(warp_sum(e0), 0, 64);
      float m1 = __shfl(warp_max(acc1), 0, 64);
      float e1 = __expf(acc1 - m1);
      float s1 = __shfl(warp_sum(e1), 0, 64);
      qk_s[h0 * 64 + lane] = e0 / s0;
      qk_s[h0 * 64 + 64 + lane] = e1 / s1;
    }
    __syncthreads();
    if (tid < 32) out[OUT_ATTW + (size_t)t * 512 + bid * 32 + tid] =
        qk_s[bid * 32 + tid];
    {
      const float* rg = (t == 0) ? qk_s : ring_s[(t >= 16) ? (t & 15) : 0];
      float av0 = 0.f, av1 = 0.f, dv0 = 0.f, dv1 = 0.f;
#pragma unroll 8
      for (int n = 0; n < 64; n++) {
        float xv = att_s[n * 65 + lane];
        av0 += qk_s[h0 * 64 + n] * xv;
        av1 += qk_s[h0 * 64 + 64 + n] * xv;
        dv0 += rg[h0 * 64 + n] * xv;
        dv1 += rg[h0 * 64 + 64 + n] * xv;
      }
      avq_s[h0 * 64 + lane] = av0;
      avq_s[h0 * 64 + 64 + lane] = av1;
      xcat_s[64 + h0 * 64 + lane] = dv0;
      xcat_s[64 + h0 * 64 + 64 + lane] = dv1;
    }
    __syncthreads();
    if (tid < 32) dava[(size_t)t * 512 + bid * 32 + tid] = xcat_s[64 + bid * 32 + tid];
    for (int i = tid; i < 512; i += 256) ring_s[t & 15][i] = qk_s[i];

    // ---- prefetch x_att(t+1) into regs (deposit after gates) ----
    float4 pf0, pf1, pf2, pf3;
    {
      int tn = (t + 1 < TT) ? t + 1 : TT - 1;
      const float4* g4 = (const float4*)(x_att + (size_t)tn * 4096);
      pf0 = g4[tid * 4 + 0];
      pf1 = g4[tid * 4 + 1];
      pf2 = g4[tid * 4 + 2];
      pf3 = g4[tid * 4 + 3];
    }

    // ---- q-GRU gates: 48 rows/block, 12/wave ----
    {
      float accg[12], acch[12];
      int rows[12];
#pragma unroll
      for (int k = 0; k < 12; k++) {
        int m = wv + 4 * k;
        rows[k] = ((m >> 4) * 256) + bid * 16 + (m & 15);
        accg[k] = 0.f;
        acch[k] = 0.f;
      }
      const float4* in4 = (const float4*)avq_s;
#pragma unroll
      for (int c0 = 0; c0 < 4; c0++) {
        int c = lane + 64 * c0;
        float4 v = in4[c];
#pragma unroll
        for (int k = 0; k < 12; k++) {
          const float4* W = (const float4*)(w_ih + (size_t)rows[k] * 1088 + 64);
          accg[k] += dot4(W[c], v);
        }
      }
      {
        const float4* h4 = (const float4*)h_s;
        float4 vh = h4[lane];
#pragma unroll
        for (int k = 0; k < 12; k++) {
          const float4* Wh = (const float4*)(w_hh + (size_t)rows[k] * 256);
          acch[k] += dot4(Wh[lane], vh);
        }
      }
#pragma unroll
      for (int k = 0; k < 12; k++) {
        int m = wv + 4 * k;
        int gate = m >> 4, i = m & 15;
        if (gate < 2) {
          float s = warp_sum(accg[k] + acch[k]);
          if (lane == 0)
            g_s[gate][i] = s + gi_fix[(size_t)t * 768 + rows[k]] + b_hh[rows[k]];
        } else {
          float sg = warp_sum(accg[k]);
          float sh = warp_sum(acch[k]);
          if (lane == 0) {
            g_s[2][i] = sg + gi_fix[(size_t)t * 768 + rows[k]];
            g_s[3][i] = sh + b_hh[rows[k]];
          }
        }
      }
    }
    // ---- dec-GRU gates: 48 rows/block, 12/wave ----
    {
      float accg[12], acch[12];
      int rows[12];
#pragma unroll
      for (int k = 0; k < 12; k++) {
        int m = wv + 4 * k;
        rows[k] = ((m >> 4) * 256) + bid * 16 + (m & 15);
        accg[k] = 0.f;
        acch[k] = 0.f;
      }
      const float4* x4 = (const float4*)xcat_s;
#pragma unroll
      for (int c0 = 0; c0 < 3; c0++) {
        int c = lane + 64 * c0;
        if (c < 144) {
          float4 v = x4[c];
#pragma unroll
          for (int k = 0; k < 12; k++) {
            const float4* W = (const float4*)(dwih + (size_t)rows[k] * 576);
            accg[k] += dot4(W[c], v);
          }
        }
      }
      {
        const float4* dh4 = (const float4*)dech_s;
        float4 vh = dh4[lane];
#pragma unroll
        for (int k = 0; k < 12; k++) {
          const float4* Wh = (const float4*)(dwhh + (size_t)rows[k] * 256);
          acch[k] += dot4(Wh[lane], vh);
        }
      }
#pragma unroll
      for (int k = 0; k < 12; k++) {
        int m = wv + 4 * k;
        int gate = m >> 4, i = m & 15;
        if (gate < 2) {
          float s = warp_sum(accg[k] + acch[k]);
          if (lane == 0)
            dg_s[gate][i] = s + dbih[rows[k]] + dbhh[rows[k]];
        } else {
          float sg = warp_sum(accg[k]);
          float sh = warp_sum(acch[k]);
          if (lane == 0) {
            dg_s[2][i] = sg + dbih[rows[k]];
            dg_s[3][i] = sh + dbhh[rows[k]];
          }
        }
      }
    }
    __syncthreads();
    // ---- combine + mailbox write (tag t+1, parity t) ----
    if (tid < 16) {
      float r = sigf(g_s[0][tid]), z = sigf(g_s[1][tid]);
      float nn = tanhf(g_s[2][tid] + r * g_s[3][tid]);
      float h2 = (1.f - z) * nn + z * h_s[bid * 16 + tid];
      astore64(&mb[(size_t)(t & 1) * 512 + bid * 32 + tid], mbpack(h2, (unsigned)(t + 1)));
    } else if (tid < 32) {
      int i = tid - 16;
      float r = sigf(dg_s[0][i]), z = sigf(dg_s[1][i]);
      float nn = tanhf(dg_s[2][i] + r * dg_s[3][i]);
      float d2 = (1.f - z) * nn + z * dech_s[bid * 16 + i];
      astore64(&mb[(size_t)(t & 1) * 512 + bid * 32 + 16 + i], mbpack(d2, (unsigned)(t + 1)));
      dec_hist[(size_t)t * 256 + bid * 16 + i] = d2;
    }
    // ---- deposit prefetched tile (att_s free; readers done pre-barrier) ----
    {
      int row = tid >> 2, c0 = (tid & 3) * 16;
      float* d = &att_s[row * 65 + c0];
      d[0] = pf0.x; d[1] = pf0.y; d[2] = pf0.z; d[3] = pf0.w;
      d[4] = pf1.x; d[5] = pf1.y; d[6] = pf1.z; d[7] = pf1.w;
      d[8] = pf2.x; d[9] = pf2.y; d[10] = pf2.z; d[11] = pf2.w;
      d[12] = pf3.x; d[13] = pf3.y; d[14] = pf3.z; d[15] = pf3.w;
    }
  }
}

// ---------------- feat assembly: [dec_h | x_fix | dec_att_a] ----------------
__global__ void featcopy(const float* __restrict__ dec_hist,
                         const float* __restrict__ x_fix,
                         const float* __restrict__ dava,
                         float* __restrict__ feat) {
  int t = blockIdx.x, tid = threadIdx.x;
  float* f = feat + (size_t)t * 832;
  f[tid] = dec_hist[(size_t)t * 256 + tid];
  if (tid < 64) f[256 + tid] = x_fix[t * 64 + tid];
  for (int i = tid; i < 512; i += 256) f[320 + i] = dava[(size_t)t * 512 + i];
}

// ---------------- final MLP ----------------
__global__ void __launch_bounds__(256) final_k(
    const float* __restrict__ x_att,
    const float* __restrict__ s,      // [2048,256] shared part incl. b1
    const float* __restrict__ w1,     // dec_hid_w [256,896]
    const float* __restrict__ w2T,    // [256,64]
    const float* __restrict__ b2,     // [64]
    float* __restrict__ pred) {
  __shared__ float att_s[4096];
  __shared__ float s_s[256];
  __shared__ float hid_s[32 * 256];
  int t = blockIdx.x, tid = threadIdx.x, lane = tid & 63, wv = tid >> 6;
  for (int i = tid; i < 4096; i += 256) att_s[i] = x_att[(size_t)t * 4096 + i];
  s_s[tid] = s[(size_t)t * 256 + tid];
  float4 w1v[16];
  const float4* W1a4 = (const float4*)(w1 + (size_t)tid * 896 + 832);
#pragma unroll
  for (int q = 0; q < 16; q++) w1v[q] = W1a4[q];
  float bb = b2[lane];
  __syncthreads();
  for (int ch = 0; ch < 2; ch++) {
    for (int nl = 0; nl < 32; nl++) {
      int n = ch * 32 + nl;
      const float4* a4 = (const float4*)(att_s + n * 64);
      float acc = s_s[tid];
#pragma unroll
      for (int q = 0; q < 16; q++) acc += dot4(w1v[q], a4[q]);
      hid_s[nl * 256 + tid] = fmaxf(acc, 0.f);
    }
    __syncthreads();
    float accb[8];
#pragma unroll
    for (int j = 0; j < 8; j++) accb[j] = bb;
    for (int r = 0; r < 256; r++) {
      float w = w2T[r * 64 + lane];
#pragma unroll
      for (int j = 0; j < 8; j++) accb[j] += w * hid_s[(wv * 8 + j) * 256 + r];
    }
#pragma unroll
    for (int j = 0; j < 8; j++) {
      int n = ch * 32 + wv * 8 + j;
      pred[(size_t)t * 4096 + n * 64 + lane] = fmaxf(accb[j], 0.f);
    }
    __syncthreads();
  }
}

extern "C" void kernel_launch(void* const* d_in, const int* in_sizes, int n_in,
                              void* d_out, int out_size, void* d_ws, size_t ws_size,
                              hipStream_t stream) {
  const float* x_fix = (const float*)d_in[0];
  const float* x_att = (const float*)d_in[1];
  const float* qwih = (const float*)d_in[3];
  const float* qwhh = (const float*)d_in[4];
  const float* qbih = (const float*)d_in[5];
  const float* qbhh = (const float*)d_in[6];
  const float* qhw = (const float*)d_in[7];
  const float* qhb = (const float*)d_in[8];
  const float* wq = (const float*)d_in[9];
  const float* dwih = (const float*)d_in[10];
  const float* dwhh = (const float*)d_in[11];
  const float* dbih = (const float*)d_in[12];
  const float* dbhh = (const float*)d_in[13];
  const float* w1 = (const float*)d_in[14];
  const float* b1 = (const float*)d_in[15];
  const float* w2 = (const float*)d_in[16];
  const float* b2 = (const float*)d_in[17];
  float* out = (float*)d_out;

  char* ws = (char*)d_ws;
  unsigned long long* mbx = (unsigned long long*)(ws + WSO_MB);
  float* gi_fix = (float*)(ws + WSO_GIFIX);
  float* hid_fix = (float*)(ws + WSO_HIDFIX);
  float* qhwT_h = (float*)(ws + WSO_QHWTH);
  float* qhwT_a = (float*)(ws + WSO_QHWTA);
  float* w2T = (float*)(ws + WSO_W2T);
  float* dava = (float*)(ws + WSO_DAVA);
  float* dec_hist = (float*)(ws + WSO_DECH);
  float* feat = (float*)(ws + WSO_FEAT);
  float* sbuf = (float*)(ws + WSO_SBUF);

  // zero mailbox tags — required every launch (ws re-poisoned)
  hipMemsetAsync(ws, 0, 8192, stream);

  transpose_k<<<832, 256, 0, stream>>>(qhw, w2, qhwT_h, qhwT_a, w2T);
  gemm64<<<dim3(32, 12), 256, 0, stream>>>(x_fix, 64, qwih, 1088, 0, qbih,
                                           gi_fix, 768, 64);
  gemm64<<<dim3(32, 4), 256, 0, stream>>>(x_fix, 64, qhw, 832, 256, qhb,
                                          hid_fix, 256, 64);

  seq_kernel<<<NBLK, 256, 0, stream>>>(x_fix, x_att, qwih, qwhh, qbhh,
                                       qhwT_h, qhwT_a, wq,
                                       dwih, dwhh, dbih, dbhh, gi_fix, hid_fix,
                                       mbx, dava, dec_hist, out);

  featcopy<<<2048, 256, 0, stream>>>(dec_hist, x_fix, dava, feat);
  gemm64<<<dim3(32, 4), 256, 0, stream>>>(feat, 832, w1, 896, 0, b1,
                                          sbuf, 256, 832);
  final_k<<<2048, 256, 0, stream>>>(x_att, sbuf, w1, w2T, b2, out);
}

// Round 4
// 23044.426 us; speedup vs baseline: 10.1899x; 10.1899x over previous
//
#include <hip/hip_runtime.h>
#include <math.h>

// Problem constants
#define TT 2048
#define HZ 16
#define NBLK 32
#define NTH 512

// d_out layout (floats): pred | attw | q_gru_n | dec_gru_n | query_n
#define OUT_ATTW   (2048*64*64)            // 8388608
#define OUT_QGRU   (OUT_ATTW + 2048*8*64)  // 9437184
#define OUT_DECGRU (OUT_QGRU + 256)        // 9437440
#define OUT_QN     (OUT_DECGRU + 256)      // 9437696

// d_ws layout (bytes)
#define WSO_MB1    0                               // ulong[2][512]
#define WSO_MB2    8192                            // ulong[2][256]
#define WSO_MB3    12288                           // ulong[2][512]
#define WSO_MBEND  20480
#define WSO_GIFIX  20480                           // float[2048][768]
#define WSO_HIDFIX (WSO_GIFIX + 2048*768*4)        // float[2048][256]
#define WSO_WQT    (WSO_HIDFIX + 2048*256*4)       // float[512][256]
#define WSO_W2T    (WSO_WQT + 512*256*4)           // float[256][64]
#define WSO_DAVA   (WSO_W2T + 256*64*4)            // float[2048][512]
#define WSO_DECH   (WSO_DAVA + 2048*512*4)         // float[2048][256]
#define WSO_FEAT   (WSO_DECH + 2048*256*4)         // float[2048][832]
#define WSO_SBUF   (WSO_FEAT + 2048*832*4)         // float[2048][256]

__device__ __forceinline__ float warp_sum(float v) {
#pragma unroll
  for (int o = 32; o > 0; o >>= 1) v += __shfl_down(v, o, 64);
  return v;
}
__device__ __forceinline__ float warp_max(float v) {
#pragma unroll
  for (int o = 32; o > 0; o >>= 1) v = fmaxf(v, __shfl_down(v, o, 64));
  return v;
}
__device__ __forceinline__ float sigf(float x) { return 1.f / (1.f + __expf(-x)); }
__device__ __forceinline__ float dot4(float4 a, float4 b) {
  return a.x*b.x + a.y*b.y + a.z*b.z + a.w*b.w;
}
__device__ __forceinline__ unsigned long long aload64(const unsigned long long* p) {
  return __hip_atomic_load(p, __ATOMIC_RELAXED, __HIP_MEMORY_SCOPE_AGENT);
}
__device__ __forceinline__ void astore64(unsigned long long* p, unsigned long long v) {
  __hip_atomic_store(p, v, __ATOMIC_RELAXED, __HIP_MEMORY_SCOPE_AGENT);
}
__device__ __forceinline__ unsigned long long mbpack(float f, unsigned tag) {
  return ((unsigned long long)tag << 32) | (unsigned long long)__float_as_uint(f);
}
// Poll one tagged slot; payload rides the tag word (data-carrying barrier).
__device__ __forceinline__ float mbpoll(const unsigned long long* p, unsigned tag) {
  unsigned long long v = aload64(p);
  while ((unsigned)(v >> 32) != tag) {
    __builtin_amdgcn_s_sleep(1);
    v = aload64(p);
  }
  return __uint_as_float((unsigned)v);
}

// ---------------- transpose of weight_q and dec_out_w ----------------
__global__ void transpose_k(const float* __restrict__ wq,   // [256,512]
                            const float* __restrict__ w2,   // [64,256]
                            float* __restrict__ wqT,        // [512,256]
                            float* __restrict__ w2T) {      // [256,64]
  int g = blockIdx.x * 256 + threadIdx.x;
  if (blockIdx.x < 512) {
    int j = g >> 8, c = g & 255;
    wqT[g] = wq[c * 512 + j];
  } else {
    int e = g - 512 * 256;
    int r = e >> 6, a = e & 63;
    w2T[e] = w2[a * 256 + r];
  }
}

// ---------------- generic tiled GEMM: C[t][r] = bias[r] + sum_k X[t][k]*W[r][woff+k]
__global__ void __launch_bounds__(256) gemm64(
    const float* __restrict__ X, int ldx,
    const float* __restrict__ W, int ldw, int woff,
    const float* __restrict__ bias,
    float* __restrict__ C, int crows, int K) {
  __shared__ float Xs[64 * 65];
  __shared__ float Ws[64 * 65];
  int t0 = blockIdx.x * 64, r0 = blockIdx.y * 64;
  int tid = threadIdx.x;
  int u = tid & 15, v = tid >> 4;
  float acc[4][4];
#pragma unroll
  for (int i = 0; i < 4; i++)
#pragma unroll
    for (int j = 0; j < 4; j++) acc[i][j] = 0.f;

  for (int kc = 0; kc < K; kc += 64) {
    for (int idx = tid; idx < 4096; idx += 256) {
      int row = idx >> 6, col = idx & 63;
      Xs[row * 65 + col] = X[(size_t)(t0 + row) * ldx + kc + col];
      Ws[row * 65 + col] = W[(size_t)(r0 + row) * ldw + woff + kc + col];
    }
    __syncthreads();
#pragma unroll 8
    for (int k = 0; k < 64; k++) {
      float xs[4], ws[4];
#pragma unroll
      for (int i = 0; i < 4; i++) xs[i] = Xs[(v + 16 * i) * 65 + k];
#pragma unroll
      for (int j = 0; j < 4; j++) ws[j] = Ws[(u + 16 * j) * 65 + k];
#pragma unroll
      for (int i = 0; i < 4; i++)
#pragma unroll
        for (int j = 0; j < 4; j++) acc[i][j] += xs[i] * ws[j];
    }
    __syncthreads();
  }
#pragma unroll
  for (int i = 0; i < 4; i++)
#pragma unroll
    for (int j = 0; j < 4; j++) {
      int t = t0 + v + 16 * i, r = r0 + u + 16 * j;
      C[(size_t)t * crows + r] = acc[i][j] + bias[r];
    }
}

// -------- fused sequential kernel: distributed compute, 3 mailbox exchanges/step
__global__ void __launch_bounds__(512) seq_kernel(
    const float* __restrict__ x_fix,    // [2048,64]
    const float* __restrict__ x_att,    // [2048,64,64]
    const float* __restrict__ w_ih,     // [768,1088]
    const float* __restrict__ w_hh,     // [768,256]
    const float* __restrict__ b_hh,     // [768]
    const float* __restrict__ q_hid_w,  // [256,832]
    const float* __restrict__ wqT,      // [512,256]
    const float* __restrict__ dwih,     // [768,576]
    const float* __restrict__ dwhh,     // [768,256]
    const float* __restrict__ dbih,     // [768]
    const float* __restrict__ dbhh,     // [768]
    const float* __restrict__ gi_fix,   // [2048,768]
    const float* __restrict__ hid_fix,  // [2048,256]
    unsigned long long* __restrict__ mb1,  // [2][512] h2|dech
    unsigned long long* __restrict__ mb2,  // [2][256] hid
    unsigned long long* __restrict__ mb3,  // [2][512] query
    float* __restrict__ dava,           // [2048,512]
    float* __restrict__ dec_hist,       // [2048,256]
    float* __restrict__ out) {
  __shared__ float att_s[64 * 65];             // x_att tile (t)
  __shared__ float ring_s[16][512];            // attw ring
  __shared__ __align__(16) float avq_s[1024];  // [attv(512) | query(512)]
  __shared__ float qk_s[512];                  // attw(t)
  __shared__ __align__(16) float xcat_s[576];  // [fix(64) | dec_att_a(512)]
  __shared__ __align__(16) float hid_s[256];
  __shared__ __align__(16) float h_s[256];
  __shared__ __align__(16) float dech_s[256];
  __shared__ float g_s[4][8];
  __shared__ float dg_s[4][8];

  const int tid = threadIdx.x;
  const int bid = blockIdx.x;
  const int lane = tid & 63, wv = tid >> 6;  // wv 0..7 (one head / wave)

  // init state + initial tile
  for (int i = tid; i < 1024; i += NTH) avq_s[i] = (i >= 512) ? 1.f : 0.f;
  if (tid < 256) { h_s[tid] = 0.f; dech_s[tid] = 0.f; }
  {
    const float4* g4 = (const float4*)x_att;
    float4 a = g4[tid * 2], b = g4[tid * 2 + 1];
    int row = tid >> 3, c0 = (tid & 7) * 8;
    float* d = &att_s[row * 65 + c0];
    d[0]=a.x; d[1]=a.y; d[2]=a.z; d[3]=a.w; d[4]=b.x; d[5]=b.y; d[6]=b.z; d[7]=b.w;
  }
  __syncthreads();

  for (int t = 0; t < TT; ++t) {
    const unsigned tg = (unsigned)(t + 1);
    const int p = t & 1;
    // ---- phase 1: fix load + tile(t+1) prefetch into regs ----
    if (tid < 64) xcat_s[tid] = x_fix[t * 64 + tid];
    float4 pfa, pfb;
    {
      int tn = (t + 1 < TT) ? t + 1 : t;
      const float4* g4 = (const float4*)(x_att + (size_t)tn * 4096);
      pfa = g4[tid * 2];
      pfb = g4[tid * 2 + 1];
    }
    // ---- phase 2: attention, wave-local (wave wv owns head wv) ----
    {
      float acc = 0.f;
#pragma unroll 16
      for (int a = 0; a < 64; a++)
        acc += avq_s[512 + wv * 64 + a] * att_s[lane * 65 + a];
      acc *= 0.125f;
      float m = __shfl(warp_max(acc), 0, 64);
      float e = __expf(acc - m);
      float s = __shfl(warp_sum(e), 0, 64);
      qk_s[wv * 64 + lane] = e / s;
    }
    {
      const float* rg = (t == 0) ? &qk_s[0] : ring_s[(t >= 16) ? (t & 15) : 0];
      float av = 0.f, dv = 0.f;
#pragma unroll 8
      for (int n = 0; n < 64; n++) {
        float xv = att_s[n * 65 + lane];
        av += qk_s[wv * 64 + n] * xv;
        dv += rg[wv * 64 + n] * xv;
      }
      avq_s[wv * 64 + lane] = av;
      xcat_s[64 + wv * 64 + lane] = dv;
    }
    __syncthreads();  // S1
    // ---- phase 4: outputs, ring update, tile deposit ----
    if (tid < 16) {
      out[OUT_ATTW + (size_t)t * 512 + bid * 16 + tid] = qk_s[bid * 16 + tid];
      dava[(size_t)t * 512 + bid * 16 + tid] = xcat_s[64 + bid * 16 + tid];
    }
    ring_s[t & 15][tid] = qk_s[tid];
    {
      int row = tid >> 3, c0 = (tid & 7) * 8;
      float* d = &att_s[row * 65 + c0];
      d[0]=pfa.x; d[1]=pfa.y; d[2]=pfa.z; d[3]=pfa.w;
      d[4]=pfb.x; d[5]=pfb.y; d[6]=pfb.z; d[7]=pfb.w;
    }
    // ---- phase 5a: q-GRU gates, 3 rows/wave (24/block) ----
    {
      float accg[3], acch[3];
      int rows[3];
#pragma unroll
      for (int k = 0; k < 3; k++) {
        int m = wv * 3 + k;
        rows[k] = ((m >> 3) * 256) + bid * 8 + (m & 7);
        accg[k] = 0.f; acch[k] = 0.f;
      }
      const float4* in4 = (const float4*)avq_s;
#pragma unroll
      for (int c0 = 0; c0 < 4; c0++) {
        int c = lane + 64 * c0;
        float4 v = in4[c];
#pragma unroll
        for (int k = 0; k < 3; k++) {
          const float4* W = (const float4*)(w_ih + (size_t)rows[k] * 1088 + 64);
          accg[k] += dot4(W[c], v);
        }
      }
      {
        const float4* h4 = (const float4*)h_s;
        float4 vh = h4[lane];
#pragma unroll
        for (int k = 0; k < 3; k++) {
          const float4* Wh = (const float4*)(w_hh + (size_t)rows[k] * 256);
          acch[k] += dot4(Wh[lane], vh);
        }
      }
#pragma unroll
      for (int k = 0; k < 3; k++) {
        int m = wv * 3 + k;
        int gate = m >> 3, idx = m & 7;
        if (gate < 2) {
          float s = warp_sum(accg[k] + acch[k]);
          if (lane == 0)
            g_s[gate][idx] = s + gi_fix[(size_t)t * 768 + rows[k]] + b_hh[rows[k]];
        } else {
          float sg = warp_sum(accg[k]);
          float sh = warp_sum(acch[k]);
          if (lane == 0) {
            g_s[2][idx] = sg + gi_fix[(size_t)t * 768 + rows[k]];
            g_s[3][idx] = sh + b_hh[rows[k]];
          }
        }
      }
    }
    // ---- phase 5b: dec-GRU gates, 3 rows/wave ----
    {
      float accg[3], acch[3];
      int rows[3];
#pragma unroll
      for (int k = 0; k < 3; k++) {
        int m = wv * 3 + k;
        rows[k] = ((m >> 3) * 256) + bid * 8 + (m & 7);
        accg[k] = 0.f; acch[k] = 0.f;
      }
      const float4* x4 = (const float4*)xcat_s;
#pragma unroll
      for (int c0 = 0; c0 < 3; c0++) {
        int c = lane + 64 * c0;
        if (c < 144) {
          float4 v = x4[c];
#pragma unroll
          for (int k = 0; k < 3; k++) {
            const float4* W = (const float4*)(dwih + (size_t)rows[k] * 576);
            accg[k] += dot4(W[c], v);
          }
        }
      }
      {
        const float4* dh4 = (const float4*)dech_s;
        float4 vh = dh4[lane];
#pragma unroll
        for (int k = 0; k < 3; k++) {
          const float4* Wh = (const float4*)(dwhh + (size_t)rows[k] * 256);
          acch[k] += dot4(Wh[lane], vh);
        }
      }
#pragma unroll
      for (int k = 0; k < 3; k++) {
        int m = wv * 3 + k;
        int gate = m >> 3, idx = m & 7;
        if (gate < 2) {
          float s = warp_sum(accg[k] + acch[k]);
          if (lane == 0)
            dg_s[gate][idx] = s + dbih[rows[k]] + dbhh[rows[k]];
        } else {
          float sg = warp_sum(accg[k]);
          float sh = warp_sum(acch[k]);
          if (lane == 0) {
            dg_s[2][idx] = sg + dbih[rows[k]];
            dg_s[3][idx] = sh + dbhh[rows[k]];
          }
        }
      }
    }
    __syncthreads();  // S2
    // ---- phase 7: combine + E1 write (tagged) ----
    if (tid < 8) {
      float r = sigf(g_s[0][tid]), z = sigf(g_s[1][tid]);
      float nn = tanhf(g_s[2][tid] + r * g_s[3][tid]);
      float h2 = (1.f - z) * nn + z * h_s[bid * 8 + tid];
      astore64(&mb1[(size_t)p * 512 + bid * 16 + tid], mbpack(h2, tg));
    } else if (tid < 16) {
      int i = tid - 8;
      float r = sigf(dg_s[0][i]), z = sigf(dg_s[1][i]);
      float nn = tanhf(dg_s[2][i] + r * dg_s[3][i]);
      float d2 = (1.f - z) * nn + z * dech_s[bid * 8 + i];
      astore64(&mb1[(size_t)p * 512 + bid * 16 + tid], mbpack(d2, tg));
      dec_hist[(size_t)t * 256 + bid * 8 + i] = d2;
    }
    // ---- phase 8: E1 poll (1 slot/thread) ----
    {
      float f = mbpoll(mb1 + (size_t)p * 512 + tid, tg);
      int b = tid >> 4, j = tid & 15;
      if (j < 8) h_s[b * 8 + j] = f;
      else dech_s[b * 8 + j - 8] = f;
    }
    __syncthreads();  // S3
    // ---- phase 10: hid row (1/wave) + E2 write ----
    {
      int row = bid * 8 + wv;
      const float4* W = (const float4*)(q_hid_w + (size_t)row * 832);
      float acc = dot4(W[lane], ((const float4*)h_s)[lane]);
      acc += dot4(W[80 + lane], ((const float4*)avq_s)[lane]);
      acc += dot4(W[144 + lane], ((const float4*)avq_s)[64 + lane]);
      float s = warp_sum(acc);
      if (lane == 0)
        astore64(&mb2[(size_t)p * 256 + row],
                 mbpack(fmaxf(s + hid_fix[(size_t)t * 256 + row], 0.f), tg));
    }
    // ---- phase 11: E2 poll ----
    if (tid < 256) hid_s[tid] = mbpoll(mb2 + (size_t)p * 256 + tid, tg);
    __syncthreads();  // S4
    // ---- phase 13: query cols (2/wave) + E3 write ----
    {
      const float4* h4 = (const float4*)hid_s;
      float4 vh = h4[lane];
#pragma unroll
      for (int cc = 0; cc < 2; cc++) {
        int j = bid * 16 + wv * 2 + cc;
        const float4* Wt = (const float4*)(wqT + (size_t)j * 256);
        float s = warp_sum(dot4(Wt[lane], vh));
        if (lane == 0) astore64(&mb3[(size_t)p * 512 + j], mbpack(s, tg));
      }
    }
    // ---- phase 14: E3 poll → query for step t+1 ----
    avq_s[512 + tid] = mbpoll(mb3 + (size_t)p * 512 + tid, tg);
    __syncthreads();  // S5
  }

  if (bid == 0) {
    if (tid < 256) {
      out[OUT_QGRU + tid] = h_s[tid];
      out[OUT_DECGRU + tid] = dech_s[tid];
    }
    out[OUT_QN + tid] = avq_s[512 + tid];
  }
}

// ---------------- feat assembly: [dec_h | x_fix | dec_att_a] ----------------
__global__ void featcopy(const float* __restrict__ dec_hist,
                         const float* __restrict__ x_fix,
                         const float* __restrict__ dava,
                         float* __restrict__ feat) {
  int t = blockIdx.x, tid = threadIdx.x;
  float* f = feat + (size_t)t * 832;
  f[tid] = dec_hist[(size_t)t * 256 + tid];
  if (tid < 64) f[256 + tid] = x_fix[t * 64 + tid];
  for (int i = tid; i < 512; i += 256) f[320 + i] = dava[(size_t)t * 512 + i];
}

// ---------------- final MLP ----------------
__global__ void __launch_bounds__(256) final_k(
    const float* __restrict__ x_att,
    const float* __restrict__ s,      // [2048,256] shared part incl. b1
    const float* __restrict__ w1,     // dec_hid_w [256,896]
    const float* __restrict__ w2T,    // [256,64]
    const float* __restrict__ b2,     // [64]
    float* __restrict__ pred) {
  __shared__ float att_s[4096];
  __shared__ float s_s[256];
  __shared__ float hid_s[32 * 256];
  int t = blockIdx.x, tid = threadIdx.x, lane = tid & 63, wv = tid >> 6;
  for (int i = tid; i < 4096; i += 256) att_s[i] = x_att[(size_t)t * 4096 + i];
  s_s[tid] = s[(size_t)t * 256 + tid];
  float4 w1v[16];
  const float4* W1a4 = (const float4*)(w1 + (size_t)tid * 896 + 832);
#pragma unroll
  for (int q = 0; q < 16; q++) w1v[q] = W1a4[q];
  float bb = b2[lane];
  __syncthreads();
  for (int ch = 0; ch < 2; ch++) {
    for (int nl = 0; nl < 32; nl++) {
      int n = ch * 32 + nl;
      const float4* a4 = (const float4*)(att_s + n * 64);
      float acc = s_s[tid];
#pragma unroll
      for (int q = 0; q < 16; q++) acc += dot4(w1v[q], a4[q]);
      hid_s[nl * 256 + tid] = fmaxf(acc, 0.f);
    }
    __syncthreads();
    float accb[8];
#pragma unroll
    for (int j = 0; j < 8; j++) accb[j] = bb;
    for (int r = 0; r < 256; r++) {
      float w = w2T[r * 64 + lane];
#pragma unroll
      for (int j = 0; j < 8; j++) accb[j] += w * hid_s[(wv * 8 + j) * 256 + r];
    }
#pragma unroll
    for (int j = 0; j < 8; j++) {
      int n = ch * 32 + wv * 8 + j;
      pred[(size_t)t * 4096 + n * 64 + lane] = fmaxf(accb[j], 0.f);
    }
    __syncthreads();
  }
}

extern "C" void kernel_launch(void* const* d_in, const int* in_sizes, int n_in,
                              void* d_out, int out_size, void* d_ws, size_t ws_size,
                              hipStream_t stream) {
  const float* x_fix = (const float*)d_in[0];
  const float* x_att = (const float*)d_in[1];
  const float* qwih = (const float*)d_in[3];
  const float* qwhh = (const float*)d_in[4];
  const float* qbih = (const float*)d_in[5];
  const float* qbhh = (const float*)d_in[6];
  const float* qhw = (const float*)d_in[7];
  const float* qhb = (const float*)d_in[8];
  const float* wq = (const float*)d_in[9];
  const float* dwih = (const float*)d_in[10];
  const float* dwhh = (const float*)d_in[11];
  const float* dbih = (const float*)d_in[12];
  const float* dbhh = (const float*)d_in[13];
  const float* w1 = (const float*)d_in[14];
  const float* b1 = (const float*)d_in[15];
  const float* w2 = (const float*)d_in[16];
  const float* b2 = (const float*)d_in[17];
  float* out = (float*)d_out;

  char* ws = (char*)d_ws;
  unsigned long long* mb1 = (unsigned long long*)(ws + WSO_MB1);
  unsigned long long* mb2 = (unsigned long long*)(ws + WSO_MB2);
  unsigned long long* mb3 = (unsigned long long*)(ws + WSO_MB3);
  float* gi_fix = (float*)(ws + WSO_GIFIX);
  float* hid_fix = (float*)(ws + WSO_HIDFIX);
  float* wqT = (float*)(ws + WSO_WQT);
  float* w2T = (float*)(ws + WSO_W2T);
  float* dava = (float*)(ws + WSO_DAVA);
  float* dec_hist = (float*)(ws + WSO_DECH);
  float* feat = (float*)(ws + WSO_FEAT);
  float* sbuf = (float*)(ws + WSO_SBUF);

  // zero mailbox tags — required every launch (ws re-poisoned)
  hipMemsetAsync(ws, 0, WSO_MBEND, stream);

  transpose_k<<<576, 256, 0, stream>>>(wq, w2, wqT, w2T);
  gemm64<<<dim3(32, 12), 256, 0, stream>>>(x_fix, 64, qwih, 1088, 0, qbih,
                                           gi_fix, 768, 64);
  gemm64<<<dim3(32, 4), 256, 0, stream>>>(x_fix, 64, qhw, 832, 256, qhb,
                                          hid_fix, 256, 64);

  seq_kernel<<<NBLK, NTH, 0, stream>>>(x_fix, x_att, qwih, qwhh, qbhh,
                                       qhw, wqT, dwih, dwhh, dbih, dbhh,
                                       gi_fix, hid_fix, mb1, mb2, mb3,
                                       dava, dec_hist, out);

  featcopy<<<2048, 256, 0, stream>>>(dec_hist, x_fix, dava, feat);
  gemm64<<<dim3(32, 4), 256, 0, stream>>>(feat, 832, w1, 896, 0, b1,
                                          sbuf, 256, 832);
  final_k<<<2048, 256, 0, stream>>>(x_att, sbuf, w1, w2T, b2, out);
}

// Round 5
// 22715.752 us; speedup vs baseline: 10.3373x; 1.0145x over previous
//
#include <hip/hip_runtime.h>
#include <math.h>

// Problem constants
#define TT 2048
#define HZ 16
#define NBLK 32
#define NTH 512

// d_out layout (floats): pred | attw | q_gru_n | dec_gru_n | query_n
#define OUT_ATTW   (2048*64*64)            // 8388608
#define OUT_QGRU   (OUT_ATTW + 2048*8*64)  // 9437184
#define OUT_DECGRU (OUT_QGRU + 256)        // 9437440
#define OUT_QN     (OUT_DECGRU + 256)      // 9437696

// d_ws layout (bytes)
#define WSO_MB1    0                               // ulong[2][512] = 8192
#define WSO_QACC   8192                            // float[3][512] = 6144
#define WSO_QCNT   14336                           // unsigned + pad (128)
#define WSO_ZEND   14464
#define WSO_GIFIX  14464                           // float[2048][768]
#define WSO_HIDFIX (WSO_GIFIX + 2048*768*4)        // float[2048][256]
#define WSO_W2T    (WSO_HIDFIX + 2048*256*4)       // float[256][64]
#define WSO_DAVA   (WSO_W2T + 256*64*4)            // float[2048][512]
#define WSO_DECH   (WSO_DAVA + 2048*512*4)         // float[2048][256]
#define WSO_FEAT   (WSO_DECH + 2048*256*4)         // float[2048][832]
#define WSO_SBUF   (WSO_FEAT + 2048*832*4)         // float[2048][256]

__device__ __forceinline__ float warp_sum(float v) {
#pragma unroll
  for (int o = 32; o > 0; o >>= 1) v += __shfl_down(v, o, 64);
  return v;
}
__device__ __forceinline__ float warp_max(float v) {
#pragma unroll
  for (int o = 32; o > 0; o >>= 1) v = fmaxf(v, __shfl_down(v, o, 64));
  return v;
}
__device__ __forceinline__ float sigf(float x) { return 1.f / (1.f + __expf(-x)); }
__device__ __forceinline__ float dot4(float4 a, float4 b) {
  return a.x*b.x + a.y*b.y + a.z*b.z + a.w*b.w;
}
__device__ __forceinline__ unsigned long long aload64(const unsigned long long* p) {
  return __hip_atomic_load(p, __ATOMIC_RELAXED, __HIP_MEMORY_SCOPE_AGENT);
}
__device__ __forceinline__ void astore64(unsigned long long* p, unsigned long long v) {
  __hip_atomic_store(p, v, __ATOMIC_RELAXED, __HIP_MEMORY_SCOPE_AGENT);
}
__device__ __forceinline__ unsigned long long mbpack(float f, unsigned tag) {
  return ((unsigned long long)tag << 32) | (unsigned long long)__float_as_uint(f);
}
// Poll one tagged slot; payload rides the tag word (data-carrying barrier).
__device__ __forceinline__ float mbpoll(const unsigned long long* p, unsigned tag) {
  unsigned long long v = aload64(p);
  while ((unsigned)(v >> 32) != tag) {
    __builtin_amdgcn_s_sleep(1);
    v = aload64(p);
  }
  return __uint_as_float((unsigned)v);
}

// ---------------- transpose of dec_out_w ----------------
__global__ void transpose_k(const float* __restrict__ w2,   // [64,256]
                            float* __restrict__ w2T) {      // [256,64]
  int e = blockIdx.x * 256 + threadIdx.x;
  int r = e >> 6, a = e & 63;
  w2T[e] = w2[a * 256 + r];
}

// ---------------- generic tiled GEMM: C[t][r] = bias[r] + sum_k X[t][k]*W[r][woff+k]
__global__ void __launch_bounds__(256) gemm64(
    const float* __restrict__ X, int ldx,
    const float* __restrict__ W, int ldw, int woff,
    const float* __restrict__ bias,
    float* __restrict__ C, int crows, int K) {
  __shared__ float Xs[64 * 65];
  __shared__ float Ws[64 * 65];
  int t0 = blockIdx.x * 64, r0 = blockIdx.y * 64;
  int tid = threadIdx.x;
  int u = tid & 15, v = tid >> 4;
  float acc[4][4];
#pragma unroll
  for (int i = 0; i < 4; i++)
#pragma unroll
    for (int j = 0; j < 4; j++) acc[i][j] = 0.f;

  for (int kc = 0; kc < K; kc += 64) {
    for (int idx = tid; idx < 4096; idx += 256) {
      int row = idx >> 6, col = idx & 63;
      Xs[row * 65 + col] = X[(size_t)(t0 + row) * ldx + kc + col];
      Ws[row * 65 + col] = W[(size_t)(r0 + row) * ldw + woff + kc + col];
    }
    __syncthreads();
#pragma unroll 8
    for (int k = 0; k < 64; k++) {
      float xs[4], ws[4];
#pragma unroll
      for (int i = 0; i < 4; i++) xs[i] = Xs[(v + 16 * i) * 65 + k];
#pragma unroll
      for (int j = 0; j < 4; j++) ws[j] = Ws[(u + 16 * j) * 65 + k];
#pragma unroll
      for (int i = 0; i < 4; i++)
#pragma unroll
        for (int j = 0; j < 4; j++) acc[i][j] += xs[i] * ws[j];
    }
    __syncthreads();
  }
#pragma unroll
  for (int i = 0; i < 4; i++)
#pragma unroll
    for (int j = 0; j < 4; j++) {
      int t = t0 + v + 16 * i, r = r0 + u + 16 * j;
      C[(size_t)t * crows + r] = acc[i][j] + bias[r];
    }
}

// -------- fused sequential kernel: E1 mailbox + query atomic-reduce per step ----
__global__ void __launch_bounds__(512) seq_kernel(
    const float* __restrict__ x_fix,    // [2048,64]
    const float* __restrict__ x_att,    // [2048,64,64]
    const float* __restrict__ w_ih,     // [768,1088]
    const float* __restrict__ w_hh,     // [768,256]
    const float* __restrict__ b_hh,     // [768]
    const float* __restrict__ q_hid_w,  // [256,832]
    const float* __restrict__ wq,       // [256,512]
    const float* __restrict__ dwih,     // [768,576]
    const float* __restrict__ dwhh,     // [768,256]
    const float* __restrict__ dbih,     // [768]
    const float* __restrict__ dbhh,     // [768]
    const float* __restrict__ gi_fix,   // [2048,768]
    const float* __restrict__ hid_fix,  // [2048,256]
    unsigned long long* __restrict__ mb1,  // [2][512] h2|dech mailbox
    float* __restrict__ qacc,           // [3][512] query accumulator
    unsigned* __restrict__ qcnt,        // arrival counter (monotonic)
    float* __restrict__ dava,           // [2048,512]
    float* __restrict__ dec_hist,       // [2048,256]
    float* __restrict__ out) {
  __shared__ float att_s[64 * 65];             // x_att tile (t)
  __shared__ float ring_s[16][512];            // attw ring
  __shared__ __align__(16) float avq_s[1024];  // [attv(512) | query(512)]
  __shared__ float qk_s[512];                  // attw(t)
  __shared__ __align__(16) float xcat_s[576];  // [fix(64) | dec_att_a(512)]
  __shared__ __align__(16) float hid8_s[8];
  __shared__ __align__(16) float h_s[256];
  __shared__ __align__(16) float dech_s[256];
  __shared__ float g_s[4][8];
  __shared__ float dg_s[4][8];

  const int tid = threadIdx.x;
  const int bid = blockIdx.x;
  const int lane = tid & 63, wv = tid >> 6;  // wv 0..7 (one head / wave)

  // init state + initial tile + fix(0)
  for (int i = tid; i < 1024; i += NTH) avq_s[i] = (i >= 512) ? 1.f : 0.f;
  if (tid < 256) { h_s[tid] = 0.f; dech_s[tid] = 0.f; }
  {
    const float4* g4 = (const float4*)x_att;
    float4 a = g4[tid * 2], b = g4[tid * 2 + 1];
    int row = tid >> 3, c0 = (tid & 7) * 8;
    float* d = &att_s[row * 65 + c0];
    d[0]=a.x; d[1]=a.y; d[2]=a.z; d[3]=a.w; d[4]=b.x; d[5]=b.y; d[6]=b.z; d[7]=b.w;
  }
  if (tid < 64) xcat_s[tid] = x_fix[tid];
  __syncthreads();

  for (int t = 0; t <= TT; ++t) {
    if (t > 0) {
      // ---- A: poll E1(t-1); deferred zero of qacc buf (t-1)%3 ----
      {
        float f = mbpoll(mb1 + (size_t)((t - 1) & 1) * 512 + tid, (unsigned)t);
        int b = tid >> 4, j = tid & 15;
        if (j < 8) h_s[b * 8 + j] = f;
        else dech_s[b * 8 + j - 8] = f;
        if (t >= 2 && tid < 16)
          __hip_atomic_store(&qacc[(size_t)((t - 1) % 3) * 512 + bid * 16 + tid],
                             0.f, __ATOMIC_RELAXED, __HIP_MEMORY_SCOPE_AGENT);
      }
      __syncthreads();
      // ---- B: hid(t-1) rows, 1/wave (8/block) ----
      {
        int row = bid * 8 + wv;
        const float4* W = (const float4*)(q_hid_w + (size_t)row * 832);
        float acc = dot4(W[lane], ((const float4*)h_s)[lane]);
        acc += dot4(W[80 + lane], ((const float4*)avq_s)[lane]);
        acc += dot4(W[144 + lane], ((const float4*)avq_s)[64 + lane]);
        float s = warp_sum(acc);
        if (lane == 0)
          hid8_s[wv] = fmaxf(s + hid_fix[(size_t)(t - 1) * 256 + row], 0.f);
      }
      __syncthreads();
      // ---- C: query partial add (1 slot/thread) ----
      {
        float hv[8];
#pragma unroll
        for (int r = 0; r < 8; r++) hv[r] = hid8_s[r];
        float partial = 0.f;
#pragma unroll
        for (int r = 0; r < 8; r++)
          partial += hv[r] * wq[(size_t)(bid * 8 + r) * 512 + tid];
        __hip_atomic_fetch_add(&qacc[(size_t)(t % 3) * 512 + tid], partial,
                               __ATOMIC_RELAXED, __HIP_MEMORY_SCOPE_AGENT);
        asm volatile("s_waitcnt vmcnt(0)" ::: "memory");
      }
      __syncthreads();
      // ---- D: arrive + poll counter ----
      if (tid == 0) {
        __hip_atomic_fetch_add(qcnt, 1u, __ATOMIC_RELAXED,
                               __HIP_MEMORY_SCOPE_AGENT);
        unsigned target = 32u * (unsigned)t;
        while (__hip_atomic_load(qcnt, __ATOMIC_RELAXED,
                                 __HIP_MEMORY_SCOPE_AGENT) < target)
          __builtin_amdgcn_s_sleep(1);
      }
      __syncthreads();
      // ---- E: read summed query(t) ----
      {
        float qv = __hip_atomic_load(&qacc[(size_t)(t % 3) * 512 + tid],
                                     __ATOMIC_RELAXED, __HIP_MEMORY_SCOPE_AGENT);
        avq_s[512 + tid] = qv;
        if (t == TT) {
          if (bid == 0) {
            if (tid < 256) {
              out[OUT_QGRU + tid] = h_s[tid];
              out[OUT_DECGRU + tid] = dech_s[tid];
            }
            out[OUT_QN + tid] = qv;
          }
          break;
        }
      }
      __syncthreads();
    }

    // ---- F: prefetch tile(t+1) + attention(t), wave-local per head ----
    float4 pfa, pfb;
    {
      int tn = (t + 1 < TT) ? t + 1 : t;
      const float4* g4 = (const float4*)(x_att + (size_t)tn * 4096);
      pfa = g4[tid * 2];
      pfb = g4[tid * 2 + 1];
    }
    {
      float acc = 0.f;
#pragma unroll 16
      for (int a = 0; a < 64; a++)
        acc += avq_s[512 + wv * 64 + a] * att_s[lane * 65 + a];
      acc *= 0.125f;
      float m = __shfl(warp_max(acc), 0, 64);
      float e = __expf(acc - m);
      float s = __shfl(warp_sum(e), 0, 64);
      qk_s[wv * 64 + lane] = e / s;
    }
    {
      const float* rg = (t == 0) ? &qk_s[0] : ring_s[(t >= 16) ? (t & 15) : 0];
      float av = 0.f, dv = 0.f;
#pragma unroll 8
      for (int n = 0; n < 64; n++) {
        float xv = att_s[n * 65 + lane];
        av += qk_s[wv * 64 + n] * xv;
        dv += rg[wv * 64 + n] * xv;
      }
      avq_s[wv * 64 + lane] = av;
      xcat_s[64 + wv * 64 + lane] = dv;
    }
    __syncthreads();  // S-F
    // ---- G: q-GRU gates (3 rows/wave) + dec-GRU gates (3 rows/wave) ----
    {
      float accg[3], acch[3];
      int rows[3];
#pragma unroll
      for (int k = 0; k < 3; k++) {
        int m = wv * 3 + k;
        rows[k] = ((m >> 3) * 256) + bid * 8 + (m & 7);
        accg[k] = 0.f; acch[k] = 0.f;
      }
      const float4* in4 = (const float4*)avq_s;
#pragma unroll
      for (int c0 = 0; c0 < 4; c0++) {
        int c = lane + 64 * c0;
        float4 v = in4[c];
#pragma unroll
        for (int k = 0; k < 3; k++) {
          const float4* W = (const float4*)(w_ih + (size_t)rows[k] * 1088 + 64);
          accg[k] += dot4(W[c], v);
        }
      }
      {
        const float4* h4 = (const float4*)h_s;
        float4 vh = h4[lane];
#pragma unroll
        for (int k = 0; k < 3; k++) {
          const float4* Wh = (const float4*)(w_hh + (size_t)rows[k] * 256);
          acch[k] += dot4(Wh[lane], vh);
        }
      }
#pragma unroll
      for (int k = 0; k < 3; k++) {
        int m = wv * 3 + k;
        int gate = m >> 3, idx = m & 7;
        if (gate < 2) {
          float s = warp_sum(accg[k] + acch[k]);
          if (lane == 0)
            g_s[gate][idx] = s + gi_fix[(size_t)t * 768 + rows[k]] + b_hh[rows[k]];
        } else {
          float sg = warp_sum(accg[k]);
          float sh = warp_sum(acch[k]);
          if (lane == 0) {
            g_s[2][idx] = sg + gi_fix[(size_t)t * 768 + rows[k]];
            g_s[3][idx] = sh + b_hh[rows[k]];
          }
        }
      }
    }
    {
      float accg[3], acch[3];
      int rows[3];
#pragma unroll
      for (int k = 0; k < 3; k++) {
        int m = wv * 3 + k;
        rows[k] = ((m >> 3) * 256) + bid * 8 + (m & 7);
        accg[k] = 0.f; acch[k] = 0.f;
      }
      const float4* x4 = (const float4*)xcat_s;
#pragma unroll
      for (int c0 = 0; c0 < 3; c0++) {
        int c = lane + 64 * c0;
        if (c < 144) {
          float4 v = x4[c];
#pragma unroll
          for (int k = 0; k < 3; k++) {
            const float4* W = (const float4*)(dwih + (size_t)rows[k] * 576);
            accg[k] += dot4(W[c], v);
          }
        }
      }
      {
        const float4* dh4 = (const float4*)dech_s;
        float4 vh = dh4[lane];
#pragma unroll
        for (int k = 0; k < 3; k++) {
          const float4* Wh = (const float4*)(dwhh + (size_t)rows[k] * 256);
          acch[k] += dot4(Wh[lane], vh);
        }
      }
#pragma unroll
      for (int k = 0; k < 3; k++) {
        int m = wv * 3 + k;
        int gate = m >> 3, idx = m & 7;
        if (gate < 2) {
          float s = warp_sum(accg[k] + acch[k]);
          if (lane == 0)
            dg_s[gate][idx] = s + dbih[rows[k]] + dbhh[rows[k]];
        } else {
          float sg = warp_sum(accg[k]);
          float sh = warp_sum(acch[k]);
          if (lane == 0) {
            dg_s[2][idx] = sg + dbih[rows[k]];
            dg_s[3][idx] = sh + dbhh[rows[k]];
          }
        }
      }
    }
    __syncthreads();  // S-G
    // ---- H: combine + E1(t) write ASAP ----
    if (tid < 8) {
      float r = sigf(g_s[0][tid]), z = sigf(g_s[1][tid]);
      float nn = tanhf(g_s[2][tid] + r * g_s[3][tid]);
      float h2 = (1.f - z) * nn + z * h_s[bid * 8 + tid];
      astore64(&mb1[(size_t)(t & 1) * 512 + bid * 16 + tid],
               mbpack(h2, (unsigned)(t + 1)));
    } else if (tid < 16) {
      int i = tid - 8;
      float r = sigf(dg_s[0][i]), z = sigf(dg_s[1][i]);
      float nn = tanhf(dg_s[2][i] + r * dg_s[3][i]);
      float d2 = (1.f - z) * nn + z * dech_s[bid * 8 + i];
      astore64(&mb1[(size_t)(t & 1) * 512 + bid * 16 + tid],
               mbpack(d2, (unsigned)(t + 1)));
      dec_hist[(size_t)t * 256 + bid * 8 + i] = d2;
    }
    // ---- I: shadow work (under other blocks' E1 skew) ----
    if (tid < 16) {
      out[OUT_ATTW + (size_t)t * 512 + bid * 16 + tid] = qk_s[bid * 16 + tid];
      dava[(size_t)t * 512 + bid * 16 + tid] = xcat_s[64 + bid * 16 + tid];
    }
    ring_s[t & 15][tid] = qk_s[tid];
    {
      int row = tid >> 3, c0 = (tid & 7) * 8;
      float* d = &att_s[row * 65 + c0];
      d[0]=pfa.x; d[1]=pfa.y; d[2]=pfa.z; d[3]=pfa.w;
      d[4]=pfb.x; d[5]=pfb.y; d[6]=pfb.z; d[7]=pfb.w;
    }
    if (tid >= 448) {
      int i = tid - 448;
      int tn = (t + 1 < TT) ? t + 1 : t;
      xcat_s[i] = x_fix[tn * 64 + i];
    }
  }
}

// ---------------- feat assembly: [dec_h | x_fix | dec_att_a] ----------------
__global__ void featcopy(const float* __restrict__ dec_hist,
                         const float* __restrict__ x_fix,
                         const float* __restrict__ dava,
                         float* __restrict__ feat) {
  int t = blockIdx.x, tid = threadIdx.x;
  float* f = feat + (size_t)t * 832;
  f[tid] = dec_hist[(size_t)t * 256 + tid];
  if (tid < 64) f[256 + tid] = x_fix[t * 64 + tid];
  for (int i = tid; i < 512; i += 256) f[320 + i] = dava[(size_t)t * 512 + i];
}

// ---------------- final MLP ----------------
__global__ void __launch_bounds__(256) final_k(
    const float* __restrict__ x_att,
    const float* __restrict__ s,      // [2048,256] shared part incl. b1
    const float* __restrict__ w1,     // dec_hid_w [256,896]
    const float* __restrict__ w2T,    // [256,64]
    const float* __restrict__ b2,     // [64]
    float* __restrict__ pred) {
  __shared__ float att_s[4096];
  __shared__ float s_s[256];
  __shared__ float hid_s[32 * 256];
  int t = blockIdx.x, tid = threadIdx.x, lane = tid & 63, wv = tid >> 6;
  for (int i = tid; i < 4096; i += 256) att_s[i] = x_att[(size_t)t * 4096 + i];
  s_s[tid] = s[(size_t)t * 256 + tid];
  float4 w1v[16];
  const float4* W1a4 = (const float4*)(w1 + (size_t)tid * 896 + 832);
#pragma unroll
  for (int q = 0; q < 16; q++) w1v[q] = W1a4[q];
  float bb = b2[lane];
  __syncthreads();
  for (int ch = 0; ch < 2; ch++) {
    for (int nl = 0; nl < 32; nl++) {
      int n = ch * 32 + nl;
      const float4* a4 = (const float4*)(att_s + n * 64);
      float acc = s_s[tid];
#pragma unroll
      for (int q = 0; q < 16; q++) acc += dot4(w1v[q], a4[q]);
      hid_s[nl * 256 + tid] = fmaxf(acc, 0.f);
    }
    __syncthreads();
    float accb[8];
#pragma unroll
    for (int j = 0; j < 8; j++) accb[j] = bb;
    for (int r = 0; r < 256; r++) {
      float w = w2T[r * 64 + lane];
#pragma unroll
      for (int j = 0; j < 8; j++) accb[j] += w * hid_s[(wv * 8 + j) * 256 + r];
    }
#pragma unroll
    for (int j = 0; j < 8; j++) {
      int n = ch * 32 + wv * 8 + j;
      pred[(size_t)t * 4096 + n * 64 + lane] = fmaxf(accb[j], 0.f);
    }
    __syncthreads();
  }
}

extern "C" void kernel_launch(void* const* d_in, const int* in_sizes, int n_in,
                              void* d_out, int out_size, void* d_ws, size_t ws_size,
                              hipStream_t stream) {
  const float* x_fix = (const float*)d_in[0];
  const float* x_att = (const float*)d_in[1];
  const float* qwih = (const float*)d_in[3];
  const float* qwhh = (const float*)d_in[4];
  const float* qbih = (const float*)d_in[5];
  const float* qbhh = (const float*)d_in[6];
  const float* qhw = (const float*)d_in[7];
  const float* qhb = (const float*)d_in[8];
  const float* wq = (const float*)d_in[9];
  const float* dwih = (const float*)d_in[10];
  const float* dwhh = (const float*)d_in[11];
  const float* dbih = (const float*)d_in[12];
  const float* dbhh = (const float*)d_in[13];
  const float* w1 = (const float*)d_in[14];
  const float* b1 = (const float*)d_in[15];
  const float* w2 = (const float*)d_in[16];
  const float* b2 = (const float*)d_in[17];
  float* out = (float*)d_out;

  char* ws = (char*)d_ws;
  unsigned long long* mb1 = (unsigned long long*)(ws + WSO_MB1);
  float* qacc = (float*)(ws + WSO_QACC);
  unsigned* qcnt = (unsigned*)(ws + WSO_QCNT);
  float* gi_fix = (float*)(ws + WSO_GIFIX);
  float* hid_fix = (float*)(ws + WSO_HIDFIX);
  float* w2T = (float*)(ws + WSO_W2T);
  float* dava = (float*)(ws + WSO_DAVA);
  float* dec_hist = (float*)(ws + WSO_DECH);
  float* feat = (float*)(ws + WSO_FEAT);
  float* sbuf = (float*)(ws + WSO_SBUF);

  // zero mailbox tags + query accumulator + counter — required every launch
  hipMemsetAsync(ws, 0, WSO_ZEND, stream);

  transpose_k<<<64, 256, 0, stream>>>(w2, w2T);
  gemm64<<<dim3(32, 12), 256, 0, stream>>>(x_fix, 64, qwih, 1088, 0, qbih,
                                           gi_fix, 768, 64);
  gemm64<<<dim3(32, 4), 256, 0, stream>>>(x_fix, 64, qhw, 832, 256, qhb,
                                          hid_fix, 256, 64);

  seq_kernel<<<NBLK, NTH, 0, stream>>>(x_fix, x_att, qwih, qwhh, qbhh,
                                       qhw, wq, dwih, dwhh, dbih, dbhh,
                                       gi_fix, hid_fix, mb1, qacc, qcnt,
                                       dava, dec_hist, out);

  featcopy<<<2048, 256, 0, stream>>>(dec_hist, x_fix, dava, feat);
  gemm64<<<dim3(32, 4), 256, 0, stream>>>(feat, 832, w1, 896, 0, b1,
                                          sbuf, 256, 832);
  final_k<<<2048, 256, 0, stream>>>(x_att, sbuf, w1, w2T, b2, out);
}